// Round 1
// baseline (67.986 us; speedup 1.0000x reference)
//
#include <hip/hip_runtime.h>

#define SEQ 1024

// LDS row layout: row k starts at word k*8 + (k>>7)*4.
// The per-128-row (per key-chunk) +4-word offset makes the 8 chunk rows that a
// wave reads simultaneously tile all 32 LDS banks exactly once (conflict-free
// ds_read_b128); a plain k*8 layout would be 8-way conflicted (chunk stride
// 128*8 words == 0 mod 32 banks).
static __device__ __forceinline__ int lds_addr(int k) {
    return (k << 3) + ((k >> 7) << 2);
}

// Closed-form qlayer for one token row y[0..7]:
// effective angles a = {y0+t0, y1+t1, y2+y3+t2, t3, y4+t4, y5+t5, y6+t6, y7+t7}
// c_w = cos(a_w);  out[0] = c1..c7, out[w] = c0..cw (w>=1).
static __device__ __forceinline__ void qrow(const float th[8], const float y[8], float o[8]) {
    float a[8];
    a[0] = y[0] + th[0];
    a[1] = y[1] + th[1];
    a[2] = y[2] + y[3] + th[2];
    a[3] = th[3];
    a[4] = y[4] + th[4];
    a[5] = y[5] + th[5];
    a[6] = y[6] + th[6];
    a[7] = y[7] + th[7];
    float c[8];
#pragma unroll
    for (int w = 0; w < 8; ++w) c[w] = __cosf(a[w]);
    o[1] = c[0] * c[1];
#pragma unroll
    for (int w = 2; w < 8; ++w) o[w] = o[w - 1] * c[w];
    float s = c[7];
#pragma unroll
    for (int w = 6; w >= 1; --w) s *= c[w];
    o[0] = s;
}

// One fused kernel: qlayer -> 2-head attention (dk=4) -> qlayer.
// Grid: 16 batches * 32 query-tiles = 512 blocks, 256 threads.
// Stage 1: block recomputes h[b] (1024x8) into LDS (redundant across the 32
//          blocks of a batch, but ~8K __cosf per block is negligible).
// Stage 2: lane = (q_in_wave<<3)|chunk; 8 lanes split the 1024 keys into 8
//          chunks of 128; unnormalized softmax (scores bounded in [-2,2] since
//          |h|<=1, so exp() cannot overflow -> no running max needed);
//          shfl_xor reduction over chunk lanes; chunk==0 lane runs the second
//          qlayer and stores the output row.
__global__ __launch_bounds__(256, 2) void mhaq_fused(const float* __restrict__ x,
                                                     const float* __restrict__ theta,
                                                     float* __restrict__ out) {
    __shared__ __align__(16) float h_lds[8 * SEQ + 7 * 4 + 4];  // 8224 words, 32.1 KB

    const int b   = blockIdx.x >> 5;         // batch
    const int qof = (blockIdx.x & 31) << 5;  // first query of this block's tile
    const int t   = threadIdx.x;

    float th[8];
#pragma unroll
    for (int w = 0; w < 8; ++w) th[w] = theta[w];

    // ---- Stage 1: h[b] into LDS ----
    const float4* xb = (const float4*)(x + (size_t)b * SEQ * 8);
#pragma unroll
    for (int r = 0; r < 4; ++r) {
        const int k  = t + (r << 8);
        const float4 v0 = xb[2 * k];
        const float4 v1 = xb[2 * k + 1];
        const float y[8] = {v0.x, v0.y, v0.z, v0.w, v1.x, v1.y, v1.z, v1.w};
        float o[8];
        qrow(th, y, o);
        float4* p = (float4*)&h_lds[lds_addr(k)];
        p[0] = make_float4(o[0], o[1], o[2], o[3]);
        p[1] = make_float4(o[4], o[5], o[6], o[7]);
    }
    __syncthreads();

    // ---- Stage 2: attention ----
    const int lane  = t & 63;
    const int wv    = t >> 6;
    const int qiw   = lane >> 3;   // query within wave: 0..7
    const int chunk = lane & 7;    // key chunk: 0..7
    const int q     = qof + (wv << 3) + qiw;

    float qv[8];
    {
        const float* qp = &h_lds[lds_addr(q)];
#pragma unroll
        for (int d = 0; d < 8; ++d) qv[d] = qp[d] * 0.5f;  // fold 1/sqrt(dk)=0.5 into Q
    }

    float l0 = 0.f, l1 = 0.f;
    float acc0[4] = {0.f, 0.f, 0.f, 0.f};
    float acc1[4] = {0.f, 0.f, 0.f, 0.f};

    int base = lds_addr(chunk << 7);
#pragma unroll 4
    for (int i = 0; i < 128; ++i) {
        const float4 k0 = *(const float4*)&h_lds[base];
        const float4 k1 = *(const float4*)&h_lds[base + 4];
        base += 8;
        const float s0 = qv[0] * k0.x + qv[1] * k0.y + qv[2] * k0.z + qv[3] * k0.w;
        const float s1 = qv[4] * k1.x + qv[5] * k1.y + qv[6] * k1.z + qv[7] * k1.w;
        const float e0 = __expf(s0);
        const float e1 = __expf(s1);
        l0 += e0;
        l1 += e1;
        acc0[0] += e0 * k0.x; acc0[1] += e0 * k0.y; acc0[2] += e0 * k0.z; acc0[3] += e0 * k0.w;
        acc1[0] += e1 * k1.x; acc1[1] += e1 * k1.y; acc1[2] += e1 * k1.z; acc1[3] += e1 * k1.w;
    }

    // reduce over the 8 chunk lanes (masks 1,2,4 stay within the 8-lane group)
#pragma unroll
    for (int m = 1; m < 8; m <<= 1) {
        l0 += __shfl_xor(l0, m);
        l1 += __shfl_xor(l1, m);
#pragma unroll
        for (int d = 0; d < 4; ++d) {
            acc0[d] += __shfl_xor(acc0[d], m);
            acc1[d] += __shfl_xor(acc1[d], m);
        }
    }

    if (chunk == 0) {
        const float inv0 = 1.0f / l0;
        const float inv1 = 1.0f / l1;
        float y[8];
#pragma unroll
        for (int d = 0; d < 4; ++d) {
            y[d]     = acc0[d] * inv0;
            y[4 + d] = acc1[d] * inv1;
        }
        float o[8];
        qrow(th, y, o);
        float4* op = (float4*)(out + ((size_t)(b * SEQ + q)) * 8);
        op[0] = make_float4(o[0], o[1], o[2], o[3]);
        op[1] = make_float4(o[4], o[5], o[6], o[7]);
    }
}

extern "C" void kernel_launch(void* const* d_in, const int* in_sizes, int n_in,
                              void* d_out, int out_size, void* d_ws, size_t ws_size,
                              hipStream_t stream) {
    const float* x     = (const float*)d_in[0];
    const float* theta = (const float*)d_in[1];
    float* out         = (float*)d_out;
    mhaq_fused<<<dim3(16 * 32), dim3(256), 0, stream>>>(x, theta, out);
}

// Round 2
// 66.837 us; speedup vs baseline: 1.0172x; 1.0172x over previous
//
#include <hip/hip_runtime.h>

#define SEQ 1024

typedef __attribute__((ext_vector_type(2))) float f2;

// LDS row layout: row k starts at word k*8 + (k>>7)*4.
// Stage-2 chunk c (64 keys) starts at key c*64 -> word c*512 + (c>>1)*4.
// The 16 chunk rows a wave reads simultaneously map to bank offsets
// {0,0,4,4,...,28,28}: pairs of chunks share banks (2-way, free per m136) and
// the 8 pair-groups tile all 32 banks -> effectively conflict-free b128 reads.
static __device__ __forceinline__ int lds_addr(int k) {
    return (k << 3) + ((k >> 7) << 2);
}

// Closed-form qlayer for one token row y[0..7]:
// effective angles a = {y0+t0, y1+t1, y2+y3+t2, t3, y4+t4, y5+t5, y6+t6, y7+t7}
// c_w = cos(a_w);  out[0] = c1..c7, out[w] = c0..cw (w>=1).
static __device__ __forceinline__ void qrow(const float th[8], const float y[8], float o[8]) {
    float a[8];
    a[0] = y[0] + th[0];
    a[1] = y[1] + th[1];
    a[2] = y[2] + y[3] + th[2];
    a[3] = th[3];
    a[4] = y[4] + th[4];
    a[5] = y[5] + th[5];
    a[6] = y[6] + th[6];
    a[7] = y[7] + th[7];
    float c[8];
#pragma unroll
    for (int w = 0; w < 8; ++w) c[w] = __cosf(a[w]);
    o[1] = c[0] * c[1];
#pragma unroll
    for (int w = 2; w < 8; ++w) o[w] = o[w - 1] * c[w];
    float s = c[7];
#pragma unroll
    for (int w = 6; w >= 1; --w) s *= c[w];
    o[0] = s;
}

// Fused qlayer -> 2-head attention (dk=4) -> qlayer.
// Grid: 16 batches * 64 query-tiles = 1024 blocks, 256 threads
// (4 blocks/CU, 16 waves/CU = 4 waves/SIMD for latency hiding).
// Stage 1: block recomputes h[b] (1024x8) into LDS.
// Stage 2: lane = (q_in_wave<<4)|chunk; 16 lanes split 1024 keys into 16
//          chunks of 64. Scores bounded in [-2,2] (|h|<=1) -> unnormalized
//          softmax, no running max. 0.5*log2(e) folded into Q so e = exp2(s)
//          is a single v_exp_f32. float2 accumulators to enable v_pk_fma_f32.
__global__ __launch_bounds__(256, 4) void mhaq_fused(const float* __restrict__ x,
                                                     const float* __restrict__ theta,
                                                     float* __restrict__ out) {
    __shared__ __align__(16) float h_lds[8 * SEQ + 7 * 4 + 4];  // 8224 words, 32.9 KB

    const int b   = blockIdx.x >> 6;         // batch
    const int qof = (blockIdx.x & 63) << 4;  // first query of this block's tile
    const int t   = threadIdx.x;

    float th[8];
#pragma unroll
    for (int w = 0; w < 8; ++w) th[w] = theta[w];

    // ---- Stage 1: h[b] into LDS ----
    const float4* xb = (const float4*)(x + (size_t)b * SEQ * 8);
    float4 v0[4], v1[4];
#pragma unroll
    for (int r = 0; r < 4; ++r) {  // issue all 8 loads up front
        const int k = t + (r << 8);
        v0[r] = xb[2 * k];
        v1[r] = xb[2 * k + 1];
    }
#pragma unroll
    for (int r = 0; r < 4; ++r) {
        const int k = t + (r << 8);
        const float y[8] = {v0[r].x, v0[r].y, v0[r].z, v0[r].w,
                            v1[r].x, v1[r].y, v1[r].z, v1[r].w};
        float o[8];
        qrow(th, y, o);
        float4* p = (float4*)&h_lds[lds_addr(k)];
        p[0] = make_float4(o[0], o[1], o[2], o[3]);
        p[1] = make_float4(o[4], o[5], o[6], o[7]);
    }
    __syncthreads();

    // ---- Stage 2: attention ----
    const int lane  = t & 63;
    const int wv    = t >> 6;
    const int qiw   = lane >> 4;    // query within wave: 0..3
    const int chunk = lane & 15;    // key chunk: 0..15 (64 keys each)
    const int q     = qof + (wv << 2) + qiw;

    // Q scaled by 1/sqrt(dk) * log2(e) so softmax exp becomes raw exp2.
    const float qscale = 0.5f * 1.44269504f;
    f2 qv01, qv23, qv45, qv67;
    {
        const float* qp = &h_lds[lds_addr(q)];
        qv01 = f2{qp[0], qp[1]} * qscale;
        qv23 = f2{qp[2], qp[3]} * qscale;
        qv45 = f2{qp[4], qp[5]} * qscale;
        qv67 = f2{qp[6], qp[7]} * qscale;
    }

    float l0 = 0.f, l1 = 0.f;
    f2 a01 = {0.f, 0.f}, a23 = {0.f, 0.f}, a45 = {0.f, 0.f}, a67 = {0.f, 0.f};

    int base = lds_addr(chunk << 6);
#pragma unroll 4
    for (int i = 0; i < 64; ++i) {
        const float4 k0 = *(const float4*)&h_lds[base];
        const float4 k1 = *(const float4*)&h_lds[base + 4];
        base += 8;
        const f2 k01 = {k0.x, k0.y}, k23 = {k0.z, k0.w};
        const f2 k45 = {k1.x, k1.y}, k67 = {k1.z, k1.w};
        const f2 d0 = qv01 * k01 + qv23 * k23;
        const f2 d1 = qv45 * k45 + qv67 * k67;
        const float e0 = __builtin_amdgcn_exp2f(d0.x + d0.y);
        const float e1 = __builtin_amdgcn_exp2f(d1.x + d1.y);
        l0 += e0;
        l1 += e1;
        const f2 e0v = {e0, e0}, e1v = {e1, e1};
        a01 += e0v * k01;
        a23 += e0v * k23;
        a45 += e1v * k45;
        a67 += e1v * k67;
    }

    // reduce over the 16 chunk lanes (masks 1..8 stay within the 16-lane group)
    float red[10] = {l0, l1, a01.x, a01.y, a23.x, a23.y, a45.x, a45.y, a67.x, a67.y};
#pragma unroll
    for (int m = 1; m < 16; m <<= 1) {
#pragma unroll
        for (int j = 0; j < 10; ++j) red[j] += __shfl_xor(red[j], m);
    }

    if (chunk == 0) {
        const float inv0 = 1.0f / red[0];
        const float inv1 = 1.0f / red[1];
        float y[8];
#pragma unroll
        for (int d = 0; d < 4; ++d) {
            y[d]     = red[2 + d] * inv0;
            y[4 + d] = red[6 + d] * inv1;
        }
        float o[8];
        qrow(th, y, o);
        float4* op = (float4*)(out + ((size_t)(b * SEQ + q)) * 8);
        op[0] = make_float4(o[0], o[1], o[2], o[3]);
        op[1] = make_float4(o[4], o[5], o[6], o[7]);
    }
}

extern "C" void kernel_launch(void* const* d_in, const int* in_sizes, int n_in,
                              void* d_out, int out_size, void* d_ws, size_t ws_size,
                              hipStream_t stream) {
    const float* x     = (const float*)d_in[0];
    const float* theta = (const float*)d_in[1];
    float* out         = (float*)d_out;
    mhaq_fused<<<dim3(16 * 64), dim3(256), 0, stream>>>(x, theta, out);
}